// Round 1
// baseline (1567.577 us; speedup 1.0000x reference)
//
#include <hip/hip_runtime.h>

#define R_WS 8
#define F_NF 8
#define B_BATCH 4096
#define EMB_ROWS 200000
#define EMB_DIM 64
#define NBAGS (R_WS * F_NF * B_BATCH)   // 262144 = 2^18
#define RB_SZ (R_WS * B_BATCH)          // 32768  = 2^15
#define SCAN_NB 256                     // blocks in pass1/pass3
#define SCAN_BT 256                     // threads per scan block
#define SCAN_ITEMS 4                    // items/thread -> 1024/block

// output bag o = (f<<15) + (r<<12) + b  ->  input bag i = (r<<15) + (f<<12) + b
__device__ __forceinline__ int perm_src(int o) {
    int f  = o >> 15;
    int rb = o & (RB_SZ - 1);
    int r  = rb >> 12;
    int b2 = rb & (B_BATCH - 1);
    return (r << 15) + (f << 12) + b2;
}

// Pass 1: per-block sums of lengths in input order and permuted order.
__global__ __launch_bounds__(SCAN_BT) void scan_pass1(
        const int* __restrict__ lengths, int* __restrict__ bsums) {
    int b = blockIdx.x, t = threadIdx.x;
    int base = b * (SCAN_BT * SCAN_ITEMS) + t * SCAN_ITEMS;
    int s_in = 0, s_out = 0;
#pragma unroll
    for (int k = 0; k < SCAN_ITEMS; ++k) {
        s_in  += lengths[base + k];
        s_out += lengths[perm_src(base + k)];
    }
    __shared__ int lin[SCAN_BT], lout[SCAN_BT];
    lin[t] = s_in; lout[t] = s_out;
    __syncthreads();
    for (int d = SCAN_BT / 2; d > 0; d >>= 1) {
        if (t < d) { lin[t] += lin[t + d]; lout[t] += lout[t + d]; }
        __syncthreads();
    }
    if (t == 0) { bsums[b] = lin[0]; bsums[SCAN_NB + b] = lout[0]; }
}

// Pass 2: one block exclusive-scans both 256-element block-sum arrays in place.
__global__ __launch_bounds__(SCAN_BT) void scan_pass2(int* __restrict__ bsums) {
    int t = threadIdx.x;
    __shared__ int s[2 * SCAN_NB];
    int o1 = bsums[t], o2 = bsums[SCAN_NB + t];
    s[t] = o1; s[SCAN_NB + t] = o2;
    __syncthreads();
    for (int d = 1; d < SCAN_NB; d <<= 1) {
        int a = (t >= d) ? s[t - d] : 0;
        int c = (t >= d) ? s[SCAN_NB + t - d] : 0;
        __syncthreads();
        s[t] += a; s[SCAN_NB + t] += c;
        __syncthreads();
    }
    bsums[t] = s[t] - o1;                       // exclusive
    bsums[SCAN_NB + t] = s[SCAN_NB + t] - o2;
}

// Pass 3: rebuild local scans + block offset, write full off_in / off_out.
__global__ __launch_bounds__(SCAN_BT) void scan_pass3(
        const int* __restrict__ lengths, const int* __restrict__ bsums,
        int* __restrict__ off_in, int* __restrict__ off_out) {
    int b = blockIdx.x, t = threadIdx.x;
    int base = b * (SCAN_BT * SCAN_ITEMS) + t * SCAN_ITEMS;
    int vin[SCAN_ITEMS], vout[SCAN_ITEMS];
    int tin = 0, tout = 0;
#pragma unroll
    for (int k = 0; k < SCAN_ITEMS; ++k) {
        vin[k]  = lengths[base + k];
        vout[k] = lengths[perm_src(base + k)];
        tin += vin[k]; tout += vout[k];
    }
    __shared__ int sin_[SCAN_BT], sout_[SCAN_BT];
    sin_[t] = tin; sout_[t] = tout;
    __syncthreads();
    for (int d = 1; d < SCAN_BT; d <<= 1) {
        int a = (t >= d) ? sin_[t - d] : 0;
        int c = (t >= d) ? sout_[t - d] : 0;
        __syncthreads();
        sin_[t] += a; sout_[t] += c;
        __syncthreads();
    }
    int ebase_in  = sin_[t]  - tin  + bsums[b];
    int ebase_out = sout_[t] - tout + bsums[SCAN_NB + b];
    int run_i = 0, run_o = 0;
#pragma unroll
    for (int k = 0; k < SCAN_ITEMS; ++k) {
        off_in[base + k]  = ebase_in + run_i;  run_i += vin[k];
        off_out[base + k] = ebase_out + run_o; run_o += vout[k];
    }
}

// Main: one wave (64 lanes) per output bag; lane d owns embedding dim d.
__global__ __launch_bounds__(256) void bag_kernel(
        const int* __restrict__ lengths, const int* __restrict__ indices,
        const float* __restrict__ emb,
        const int* __restrict__ off_in, const int* __restrict__ off_out,
        float* __restrict__ out_offsets, float* __restrict__ out_permuted,
        float* __restrict__ out_ly) {
    int wid  = (int)((blockIdx.x * blockDim.x + threadIdx.x) >> 6);
    int lane = threadIdx.x & 63;
    if (wid >= NBAGS) return;
    int o = wid;
    int f = o >> 15;
    int src = perm_src(o);
    int start = off_in[src];
    int len   = lengths[src];
    int obase = off_out[o];
    if (lane == 0)
        out_offsets[o] = (float)(obase - off_out[f << 15]);  // per-feature restart
    const float* etab = emb + (size_t)f * ((size_t)EMB_ROWS * EMB_DIM);
    float acc = 0.f;
    for (int j0 = 0; j0 < len; j0 += 64) {
        int rem = len - j0;
        int n = rem < 64 ? rem : 64;
        int idx = 0;
        if (lane < n) {
            idx = indices[start + j0 + lane];                 // coalesced read
            out_permuted[obase + j0 + lane] = (float)idx;     // coalesced write
        }
#pragma unroll 4
        for (int k = 0; k < n; ++k) {
            int row = __shfl(idx, k, 64);                     // broadcast index
            acc += etab[(size_t)row * EMB_DIM + lane];        // 256B/row coalesced
        }
    }
    out_ly[(size_t)o * EMB_DIM + lane] = acc;                 // coalesced
}

extern "C" void kernel_launch(void* const* d_in, const int* in_sizes, int n_in,
                              void* d_out, int out_size, void* d_ws, size_t ws_size,
                              hipStream_t stream) {
    const int*   lengths = (const int*)d_in[0];
    const int*   indices = (const int*)d_in[1];
    const float* emb     = (const float*)d_in[2];
    int T = in_sizes[1];

    int* off_in  = (int*)d_ws;            // NBAGS ints
    int* off_out = off_in + NBAGS;        // NBAGS ints
    int* bsums   = off_out + NBAGS;       // 2*SCAN_NB ints

    float* out          = (float*)d_out;
    float* out_offsets  = out;                    // F*RB  = 262144 (as fp32, exact)
    float* out_permuted = out + NBAGS;            // T     (as fp32, exact: <200000)
    float* out_ly       = out_permuted + T;       // F*RB*D = 16777216

    scan_pass1<<<SCAN_NB, SCAN_BT, 0, stream>>>(lengths, bsums);
    scan_pass2<<<1, SCAN_BT, 0, stream>>>(bsums);
    scan_pass3<<<SCAN_NB, SCAN_BT, 0, stream>>>(lengths, bsums, off_in, off_out);
    // 262144 waves, 4 waves/block -> 65536 blocks
    bag_kernel<<<NBAGS / 4, 256, 0, stream>>>(lengths, indices, emb, off_in, off_out,
                                              out_offsets, out_permuted, out_ly);
}

// Round 3
// 1025.526 us; speedup vs baseline: 1.5286x; 1.5286x over previous
//
#include <hip/hip_runtime.h>

#define R_WS 8
#define F_NF 8
#define B_BATCH 4096
#define EMB_ROWS 200000
#define EMB_DIM 64
#define NBAGS (R_WS * F_NF * B_BATCH)   // 262144 = 2^18
#define RB_SZ (R_WS * B_BATCH)          // 32768  = 2^15
#define SCAN_NB 256                     // blocks in pass1/pass3
#define SCAN_BT 256                     // threads per scan block
#define SCAN_ITEMS 4                    // items/thread -> 1024/block

typedef float vfloat4 __attribute__((ext_vector_type(4)));   // clang-native, works with nontemporal builtins

// output bag o = (f<<15) + (r<<12) + b  ->  input bag i = (r<<15) + (f<<12) + b
__device__ __forceinline__ int perm_src(int o) {
    int f  = o >> 15;
    int rb = o & (RB_SZ - 1);
    int r  = rb >> 12;
    int b2 = rb & (B_BATCH - 1);
    return (r << 15) + (f << 12) + b2;
}

// Pass 1: per-block sums of lengths in input order and permuted order.
__global__ __launch_bounds__(SCAN_BT) void scan_pass1(
        const int* __restrict__ lengths, int* __restrict__ bsums) {
    int b = blockIdx.x, t = threadIdx.x;
    int base = b * (SCAN_BT * SCAN_ITEMS) + t * SCAN_ITEMS;
    int s_in = 0, s_out = 0;
#pragma unroll
    for (int k = 0; k < SCAN_ITEMS; ++k) {
        s_in  += lengths[base + k];
        s_out += lengths[perm_src(base + k)];
    }
    __shared__ int lin[SCAN_BT], lout[SCAN_BT];
    lin[t] = s_in; lout[t] = s_out;
    __syncthreads();
    for (int d = SCAN_BT / 2; d > 0; d >>= 1) {
        if (t < d) { lin[t] += lin[t + d]; lout[t] += lout[t + d]; }
        __syncthreads();
    }
    if (t == 0) { bsums[b] = lin[0]; bsums[SCAN_NB + b] = lout[0]; }
}

// Pass 2: one block exclusive-scans both 256-element block-sum arrays in place.
__global__ __launch_bounds__(SCAN_BT) void scan_pass2(int* __restrict__ bsums) {
    int t = threadIdx.x;
    __shared__ int s[2 * SCAN_NB];
    int o1 = bsums[t], o2 = bsums[SCAN_NB + t];
    s[t] = o1; s[SCAN_NB + t] = o2;
    __syncthreads();
    for (int d = 1; d < SCAN_NB; d <<= 1) {
        int a = (t >= d) ? s[t - d] : 0;
        int c = (t >= d) ? s[SCAN_NB + t - d] : 0;
        __syncthreads();
        s[t] += a; s[SCAN_NB + t] += c;
        __syncthreads();
    }
    bsums[t] = s[t] - o1;                       // exclusive
    bsums[SCAN_NB + t] = s[SCAN_NB + t] - o2;
}

// Pass 3: rebuild local scans + block offset, write full off_in / off_out.
__global__ __launch_bounds__(SCAN_BT) void scan_pass3(
        const int* __restrict__ lengths, const int* __restrict__ bsums,
        int* __restrict__ off_in, int* __restrict__ off_out) {
    int b = blockIdx.x, t = threadIdx.x;
    int base = b * (SCAN_BT * SCAN_ITEMS) + t * SCAN_ITEMS;
    int vin[SCAN_ITEMS], vout[SCAN_ITEMS];
    int tin = 0, tout = 0;
#pragma unroll
    for (int k = 0; k < SCAN_ITEMS; ++k) {
        vin[k]  = lengths[base + k];
        vout[k] = lengths[perm_src(base + k)];
        tin += vin[k]; tout += vout[k];
    }
    __shared__ int sin_[SCAN_BT], sout_[SCAN_BT];
    sin_[t] = tin; sout_[t] = tout;
    __syncthreads();
    for (int d = 1; d < SCAN_BT; d <<= 1) {
        int a = (t >= d) ? sin_[t - d] : 0;
        int c = (t >= d) ? sout_[t - d] : 0;
        __syncthreads();
        sin_[t] += a; sout_[t] += c;
        __syncthreads();
    }
    int ebase_in  = sin_[t]  - tin  + bsums[b];
    int ebase_out = sout_[t] - tout + bsums[SCAN_NB + b];
    int run_i = 0, run_o = 0;
#pragma unroll
    for (int k = 0; k < SCAN_ITEMS; ++k) {
        off_in[base + k]  = ebase_in + run_i;  run_i += vin[k];
        off_out[base + k] = ebase_out + run_o; run_o += vout[k];
    }
}

// Main: one wave per output bag. Lane layout: g = lane>>4 picks one of 4 rows
// per step, s = lane&15 owns dims [4s..4s+3] as float4. One gather instruction
// moves 1 KB/wave (4 rows x 256 B); unroll 8 keeps ~8 KB/wave in flight.
__global__ __launch_bounds__(256) void bag_kernel(
        const int* __restrict__ lengths, const int* __restrict__ indices,
        const float* __restrict__ emb,
        const int* __restrict__ off_in, const int* __restrict__ off_out,
        float* __restrict__ out_offsets, float* __restrict__ out_permuted,
        float* __restrict__ out_ly) {
    int wid  = (int)((blockIdx.x * blockDim.x + threadIdx.x) >> 6);
    int lane = threadIdx.x & 63;
    if (wid >= NBAGS) return;
    int o = wid;
    int f = o >> 15;
    int src = perm_src(o);
    int start = off_in[src];
    int len   = lengths[src];
    int obase = off_out[o];
    if (lane == 0)
        out_offsets[o] = (float)(obase - off_out[f << 15]);  // per-feature restart
    const float* etab = emb + (size_t)f * ((size_t)EMB_ROWS * EMB_DIM);
    int g = lane >> 4;       // row-group 0..3
    int s = lane & 15;       // dim-group: owns dims 4s..4s+3
    float ax = 0.f, ay = 0.f, az = 0.f, aw = 0.f;
    for (int j0 = 0; j0 < len; j0 += 64) {
        int rem = len - j0;
        int n = rem < 64 ? rem : 64;
        int idx = 0;
        if (lane < n) {
            idx = __builtin_nontemporal_load(&indices[start + j0 + lane]); // coalesced, streaming
            __builtin_nontemporal_store((float)idx, &out_permuted[obase + j0 + lane]);
        }
        if (n == 64) {
#pragma unroll 8
            for (int jj = 0; jj < 16; ++jj) {
                int row = __shfl(idx, jj * 4 + g, 64);
                const vfloat4* p = (const vfloat4*)(etab + (size_t)row * EMB_DIM + s * 4);
                vfloat4 v = *p;                               // 1 KB/wave gather
                ax += v.x; ay += v.y; az += v.z; aw += v.w;
            }
        } else {
            int nj = (n + 3) >> 2;                            // wave-uniform
            for (int jj = 0; jj < nj; ++jj) {
                int k = jj * 4 + g;
                int row = __shfl(idx, k, 64);                 // k>=n reads idx=0, masked below
                if (k < n) {
                    const vfloat4* p = (const vfloat4*)(etab + (size_t)row * EMB_DIM + s * 4);
                    vfloat4 v = *p;
                    ax += v.x; ay += v.y; az += v.z; aw += v.w;
                }
            }
        }
    }
    // reduce the 4 row-groups (lanes s, s+16, s+32, s+48 hold partial dims 4s..4s+3)
    ax += __shfl_xor(ax, 16, 64); ay += __shfl_xor(ay, 16, 64);
    az += __shfl_xor(az, 16, 64); aw += __shfl_xor(aw, 16, 64);
    ax += __shfl_xor(ax, 32, 64); ay += __shfl_xor(ay, 32, 64);
    az += __shfl_xor(az, 32, 64); aw += __shfl_xor(aw, 32, 64);
    if (lane < 16) {                                          // 16 lanes x 16 B = 256 B store
        vfloat4 r; r.x = ax; r.y = ay; r.z = az; r.w = aw;
        __builtin_nontemporal_store(r, (vfloat4*)(out_ly + (size_t)o * EMB_DIM + s * 4));
    }
}

extern "C" void kernel_launch(void* const* d_in, const int* in_sizes, int n_in,
                              void* d_out, int out_size, void* d_ws, size_t ws_size,
                              hipStream_t stream) {
    const int*   lengths = (const int*)d_in[0];
    const int*   indices = (const int*)d_in[1];
    const float* emb     = (const float*)d_in[2];
    int T = in_sizes[1];

    int* off_in  = (int*)d_ws;            // NBAGS ints
    int* off_out = off_in + NBAGS;        // NBAGS ints
    int* bsums   = off_out + NBAGS;       // 2*SCAN_NB ints

    float* out          = (float*)d_out;
    float* out_offsets  = out;                    // F*RB  = 262144 (as fp32, exact)
    float* out_permuted = out + NBAGS;            // T     (as fp32, exact: <200000)
    float* out_ly       = out_permuted + T;       // F*RB*D = 16777216

    scan_pass1<<<SCAN_NB, SCAN_BT, 0, stream>>>(lengths, bsums);
    scan_pass2<<<1, SCAN_BT, 0, stream>>>(bsums);
    scan_pass3<<<SCAN_NB, SCAN_BT, 0, stream>>>(lengths, bsums, off_in, off_out);
    // 262144 waves, 4 waves/block -> 65536 blocks
    bag_kernel<<<NBAGS / 4, 256, 0, stream>>>(lengths, indices, emb, off_in, off_out,
                                              out_offsets, out_permuted, out_ly);
}